// Round 12
// baseline (246.773 us; speedup 1.0000x reference)
//
#include <hip/hip_runtime.h>
#include <hip/hip_bf16.h>
#include <stdint.h>

typedef unsigned int u32;
typedef unsigned long long u64;

#define IJ 16384
#define NQ 1024
#define NB 2
#define KP 256
#define NSEG 64   // ij tiles of 256 cells
#define NGRP 16   // groups of 64 row-instances
#define RCAP 8    // per-thread register candidate buffer

// ---------------- Threefry-2x32 (JAX-compatible, 20 rounds) ----------------
__device__ __forceinline__ void tf2x32(u32 k0, u32 k1, u32& x0, u32& x1) {
  u32 kx = k0 ^ k1 ^ 0x1BD11BDAu;
#define TFR(r) { x0 += x1; x1 = (x1 << (r)) | (x1 >> (32 - (r))); x1 ^= x0; }
  x0 += k0; x1 += k1;
  TFR(13) TFR(15) TFR(26) TFR(6)
  x0 += k1; x1 += kx + 1u;
  TFR(17) TFR(29) TFR(16) TFR(24)
  x0 += kx; x1 += k0 + 2u;
  TFR(13) TFR(15) TFR(26) TFR(6)
  x0 += k0; x1 += k1 + 3u;
  TFR(17) TFR(29) TFR(16) TFR(24)
  x0 += k1; x1 += kx + 4u;
  TFR(13) TFR(15) TFR(26) TFR(6)
  x0 += kx; x1 += k0 + 5u;
#undef TFR
}

// threefry_partitionable=True (JAX >= 0.5 default):
// split(key)[i]            = enc_key(0, i)
// random_bits(key,32,…)[i] = w0 ^ w1 of enc_key(hi32(i), lo32(i))
__device__ __forceinline__ void tf_subkey(u32 k0, u32 k1, u32 i, u32& s0, u32& s1) {
  u32 x0 = 0u, x1 = i;
  tf2x32(k0, k1, x0, x1);
  s0 = x0; s1 = x1;
}

__device__ __forceinline__ u32 tf_xorbits(u32 k0, u32 k1, u32 i) {
  u32 x0 = 0u, x1 = i;
  tf2x32(k0, k1, x0, x1);
  return x0 ^ x1;
}

__device__ __forceinline__ void derive_keys(int seed, u32& kq0, u32& kq1,
                                            u32& km0, u32& km1) {
  u32 k0 = 0u;
  u32 k1 = (u32)seed;
  tf_subkey(k0, k1, 0u, kq0, kq1);
  tf_subkey(k0, k1, 1u, km0, km1);
}

// JAX uniform(minval=tiny, maxval=1) -> gumbel. g in [-4.47, 16.64];
// winner bound r >= m - 21.11 => threshold m-25 is safe.
__device__ __forceinline__ float gumbel_from_bits(u32 w) {
  const float tiny = 1.17549435e-38f;
  float fl = __uint_as_float((w >> 9) | 0x3f800000u) - 1.0f;
  float u = fl * (1.0f - tiny) + tiny;
  u = fmaxf(tiny, u);
  return -logf(-logf(u));
}

__device__ __forceinline__ bool read_bool(const void* p, int idx, int is32) {
  return is32 ? (((const int*)p)[idx] != 0)
              : (((const unsigned char*)p)[idx] != 0);
}

// exact categorical value for candidate (bit-identical to R9 expression)
__device__ __forceinline__ float cat_value(float rv, float m, float s, float nv,
                                           u32 km0, u32 km1, u32 idx) {
  u32 w = tf_xorbits(km0, km1, idx);
  float gmb = gumbel_from_bits(w);
  float e = expf(rv - m);
  return logf((e / s) / nv + 1e-20f) + gmb;
}

__device__ __forceinline__ u64 pack_key(float v, int f) {
  u32 vb = __float_as_uint(v);
  u32 srt = (vb & 0x80000000u) ? ~vb : (vb | 0x80000000u);
  return ((u64)srt << 32) | (u64)(0xFFFFFFFFu - (u32)f);
}

// ---------------- setup: n_idx, bool-width detect, num_valid ---------------
__global__ void setup_kernel(const void* __restrict__ valid_q,
                             const int* __restrict__ seedp,
                             float* __restrict__ num_valid,
                             int* __restrict__ n_idx,
                             int* __restrict__ bool_is32) {
  __shared__ int sred[256];
  __shared__ int is32_s;
  const int blk = blockIdx.x, tid = threadIdx.x;
  if (blk < 4) {
    // randint(kq,(2,512),0,1024): k1,k2 = split(kq); multiplier = 0
    int s = blk * 256 + tid;  // 0..1023
    u32 kq0, kq1, km0, km1;
    derive_keys(seedp[0], kq0, kq1, km0, km1);
    u32 l0, l1;  // k2 = enc(kq, (0,1))
    tf_subkey(kq0, kq1, 1u, l0, l1);
    u32 w = tf_xorbits(l0, l1, (u32)s);
    n_idx[s] = (int)(w & 1023u);
  } else {
    const unsigned char* vb = (const unsigned char*)valid_q;
    int ones = 0;
    for (int i = tid; i < 2048; i += 256) ones += (vb[i] == 1) ? 1 : 0;
    sred[tid] = ones;
    __syncthreads();
    for (int off = 128; off > 0; off >>= 1) {
      if (tid < off) sred[tid] += sred[tid + off];
      __syncthreads();
    }
    if (tid == 0) {
      is32_s = (sred[0] < 1152) ? 1 : 0;
      bool_is32[0] = is32_s;
    }
    __syncthreads();
    const int is32 = is32_s;
    for (int b = 0; b < 2; ++b) {
      int acc = 0;
      for (int i = tid; i < NQ; i += 256)
        acc += read_bool(valid_q, b * NQ + i, is32) ? 1 : 0;
      sred[tid] = acc;
      __syncthreads();
      for (int off = 128; off > 0; off >>= 1) {
        if (tid < off) sred[tid] += sred[tid + off];
        __syncthreads();
      }
      if (tid == 0) {
        float nv = (float)sred[0];
        num_valid[b] = nv < 1.f ? 1.f : nv;
      }
      __syncthreads();
    }
  }
}

// Shared micro-kernel: 64 gathered rows x 256 cells, d-major LDS, 8x8/thread.
// Staging is lane-per-column (bank = column = lane -> 2-way, free); global
// reads are 128B-strided but L1/L2-absorbed (A tile 8 KB, B tile 32 KB).
// As/Bs contents and the d-ascending fmaf chain are identical to R9 ->
// acc is bit-identical.
#define GEMM_TILE_BODY                                                        \
  _Pragma("unroll")                                                           \
  for (int k = 0; k < 2; ++k) {                                               \
    int q = tid + k * 256;                                                    \
    int row = q & 63, dgq = q >> 6;                                           \
    int n = n_idx[t0 + row];                                                  \
    const float4 v = *(const float4*)(f_q + ((size_t)(b * NQ + n)) * 32 +     \
                                      dgq * 4);                               \
    As[dgq * 4][row] = v.x; As[dgq * 4 + 1][row] = v.y;                       \
    As[dgq * 4 + 2][row] = v.z; As[dgq * 4 + 3][row] = v.w;                   \
  }                                                                           \
  _Pragma("unroll")                                                           \
  for (int k = 0; k < 8; ++k) {                                               \
    const float4 v = *(const float4*)(f_map +                                 \
        ((size_t)(b * IJ + ij0 + tid)) * 32 + k * 4);                         \
    Bs[k * 4][tid] = v.x; Bs[k * 4 + 1][tid] = v.y;                           \
    Bs[k * 4 + 2][tid] = v.z; Bs[k * 4 + 3][tid] = v.w;                       \
  }                                                                           \
  __syncthreads();                                                            \
  const int ty = tid >> 5, tx = tid & 31;                                     \
  float acc[2][2][4][4] = {};                                                 \
  _Pragma("unroll 8")                                                         \
  for (int d = 0; d < 32; ++d) {                                              \
    float4 a0 = *(const float4*)&As[d][ty << 2];                              \
    float4 a1 = *(const float4*)&As[d][(ty << 2) + 32];                       \
    float4 b0 = *(const float4*)&Bs[d][tx << 2];                              \
    float4 b1 = *(const float4*)&Bs[d][(tx << 2) + 128];                      \
    float av[2][4] = {{a0.x, a0.y, a0.z, a0.w}, {a1.x, a1.y, a1.z, a1.w}};    \
    float bv[2][4] = {{b0.x, b0.y, b0.z, b0.w}, {b1.x, b1.y, b1.z, b1.w}};    \
    _Pragma("unroll")                                                         \
    for (int rg = 0; rg < 2; ++rg)                                            \
      _Pragma("unroll")                                                       \
      for (int cg = 0; cg < 2; ++cg)                                          \
        _Pragma("unroll")                                                     \
        for (int r = 0; r < 4; ++r)                                           \
          _Pragma("unroll")                                                   \
          for (int c = 0; c < 4; ++c)                                         \
            acc[rg][cg][r][c] = fmaf(av[rg][r], bv[cg][c], acc[rg][cg][r][c]);\
  }

// ---------------- cat1: per-(instance,seg) row max + sum(e^r) --------------
__global__ __launch_bounds__(256) void cat1_kernel(
    const float* __restrict__ f_q, const float* __restrict__ f_map,
    const float* __restrict__ temp, const int* __restrict__ n_idx,
    float* __restrict__ pmax, float* __restrict__ psum) {
  __shared__ float As[32][64];
  __shared__ float Bs[32][256];
  const int tid = threadIdx.x;
  const int g = blockIdx.y;
  const int t0 = g * 64;
  const int b = t0 >> 9;
  const int ij0 = blockIdx.x * 256;

  GEMM_TILE_BODY

  const float et = expf(temp[0]);
#pragma unroll
  for (int rg = 0; rg < 2; ++rg) {
#pragma unroll
    for (int r = 0; r < 4; ++r) {
      const int lrow = rg * 32 + (ty << 2) + r;
      float rm = 0.f, se = 0.f;
#pragma unroll
      for (int cg = 0; cg < 2; ++cg) {
        float o0 = fmaxf(acc[rg][cg][r][0], 0.f) * et;
        float o1 = fmaxf(acc[rg][cg][r][1], 0.f) * et;
        float o2 = fmaxf(acc[rg][cg][r][2], 0.f) * et;
        float o3 = fmaxf(acc[rg][cg][r][3], 0.f) * et;
        rm = fmaxf(rm, fmaxf(fmaxf(o0, o1), fmaxf(o2, o3)));
        se += expf(o0); se += expf(o1); se += expf(o2); se += expf(o3);
      }
#pragma unroll
      for (int off = 16; off > 0; off >>= 1) {
        se += __shfl_down(se, off, 32);
        rm = fmaxf(rm, __shfl_down(rm, off, 32));
      }
      if (tx == 0) {
        pmax[(size_t)(t0 + lrow) * NSEG + blockIdx.x] = rm;
        psum[(size_t)(t0 + lrow) * NSEG + blockIdx.x] = se;
      }
    }
  }
}

// ---------------- combine: m, s = Σe^r · e^-m, th = m-25; zero catbest -----
__global__ void catc_kernel(const float* __restrict__ pmax,
                            const float* __restrict__ psum,
                            float* __restrict__ row_m, float* __restrict__ row_s,
                            float* __restrict__ row_th,
                            u64* __restrict__ catbest) {
  const int t = blockIdx.x * 256 + threadIdx.x;
  if (t >= NB * 512) return;
  float m = 0.f, ss = 0.f;
#pragma unroll
  for (int s = 0; s < NSEG; ++s) m = fmaxf(m, pmax[(size_t)t * NSEG + s]);
#pragma unroll
  for (int s = 0; s < NSEG; ++s) ss += psum[(size_t)t * NSEG + s];
  row_m[t] = m;
  row_s[t] = ss * expf(-m);
  row_th[t] = m - 25.0f;
  catbest[t] = 0ULL;
}

// ---------------- cat2: recompute tile, register candidates, argmax --------
// Candidates (rv > th) held in per-thread registers (cap RCAP=8; overflow
// evals inline immediately — exact either way since the u64 (max v,
// tie->min f) lattice is order-independent). No post-GEMM LDS reads.
__global__ __launch_bounds__(256) void cat2_kernel(
    const float* __restrict__ f_q, const float* __restrict__ f_map,
    const float* __restrict__ temp, const int* __restrict__ n_idx,
    const float* __restrict__ row_m, const float* __restrict__ row_s,
    const float* __restrict__ row_th, const float* __restrict__ num_valid,
    const int* __restrict__ seedp, u64* __restrict__ catbest) {
  __shared__ float As[32][64];
  __shared__ float Bs[32][256];
  __shared__ float m_s[64], s_s[64], th_s[64];
  __shared__ u32 keys2[2];
  __shared__ u64 best[64];
  const int tid = threadIdx.x;
  const int g = blockIdx.y;
  const int t0 = g * 64;
  const int b = t0 >> 9;
  const int ij0 = blockIdx.x * 256;

  if (tid == 0) {
    u32 kq0, kq1, km0, km1;
    derive_keys(seedp[0], kq0, kq1, km0, km1);
    keys2[0] = km0; keys2[1] = km1;
  }
  if (tid < 64) {
    best[tid] = 0ULL;
    m_s[tid] = row_m[t0 + tid];
    s_s[tid] = row_s[t0 + tid];
    th_s[tid] = row_th[t0 + tid];
  }

  GEMM_TILE_BODY

  const float et = expf(temp[0]);
  const float nv = num_valid[b];
  const u32 km0 = keys2[0], km1 = keys2[1];
  float rvb[RCAP];
  int pkb[RCAP];
  int cnt = 0;
#pragma unroll
  for (int rg = 0; rg < 2; ++rg) {
#pragma unroll
    for (int r = 0; r < 4; ++r) {
      const int lrow = rg * 32 + (ty << 2) + r;
      const float th = th_s[lrow];
#pragma unroll
      for (int cg = 0; cg < 2; ++cg) {
#pragma unroll
        for (int c = 0; c < 4; ++c) {
          float rv = fmaxf(acc[rg][cg][r][c], 0.f) * et;
          if (rv > th) {
            int cell = cg * 128 + (tx << 2) + c;
            if (cnt < RCAP) {
              rvb[cnt] = rv;
              pkb[cnt] = (lrow << 8) | cell;
              ++cnt;
            } else {  // rare overflow: eval inline now (bit-exact)
              int t = t0 + lrow;
              int f = ij0 + cell;
              u32 idx = (u32)((t & 511) * IJ + f) + ((u32)b << 23);
              float v = cat_value(rv, m_s[lrow], s_s[lrow], nv, km0, km1, idx);
              atomicMax(&best[lrow], pack_key(v, f));
            }
          }
        }
      }
    }
  }
#pragma unroll
  for (int k = 0; k < RCAP; ++k) {
    if (k < cnt) {
      int mm = pkb[k];
      int lrow = mm >> 8, cell = mm & 255;
      int t = t0 + lrow;
      int f = ij0 + cell;
      u32 idx = (u32)((t & 511) * IJ + f) + ((u32)b << 23);
      float v = cat_value(rvb[k], m_s[lrow], s_s[lrow], nv, km0, km1, idx);
      atomicMax(&best[lrow], pack_key(v, f));
    }
  }
  __syncthreads();
  if (tid < 64 && best[tid] != 0ULL) atomicMax(&catbest[t0 + tid], best[tid]);
}

// ---------------- pose hypotheses (R, t); m_flat decoded from catbest ------
__global__ void pose_kernel(const float* __restrict__ q_xy,
                            const int* __restrict__ n_idx,
                            const u64* __restrict__ catbest,
                            float4* __restrict__ poses) {
  const int idx = blockIdx.x * 256 + threadIdx.x;  // 0..511
  if (idx >= NB * KP) return;
  const int b = idx >> 8, k = idx & 255;
  const int t0 = b * 512 + 2 * k, t1 = t0 + 1;
  const int na = n_idx[t0], nb = n_idx[t1];
  const float2 q0 = ((const float2*)q_xy)[(size_t)b * NQ + na];
  const float2 q1 = ((const float2*)q_xy)[(size_t)b * NQ + nb];
  const int ma = (int)(0xFFFFFFFFu - (u32)(catbest[t0] & 0xFFFFFFFFull));
  const int mb = (int)(0xFFFFFFFFu - (u32)(catbest[t1] & 0xFFFFFFFFull));
  const float m0x = ((float)(ma >> 7) + 0.5f) * 0.5f;
  const float m0y = ((float)(ma & 127) + 0.5f) * 0.5f;
  const float m1x = ((float)(mb >> 7) + 0.5f) * 0.5f;
  const float m1y = ((float)(mb & 127) + 0.5f) * 0.5f;
  const float dqx = q1.x - q0.x, dqy = q1.y - q0.y;
  const float dmx = m1x - m0x, dmy = m1y - m0y;
  const float theta = atan2f(dmy, dmx) - atan2f(dqy, dqx);
  const float c = cosf(theta), s = sinf(theta);
  const float tx = m0x - (c * q0.x - s * q0.y);
  const float ty = m0y - (s * q0.x + c * q0.y);
  poses[idx] = make_float4(c, s, tx, ty);
}

// ---------------- score: recompute gathered sim values on the fly ----------
__global__ __launch_bounds__(256) void score_kernel(
    const float* __restrict__ f_q, const float* __restrict__ f_map,
    const float* __restrict__ temp, const float* __restrict__ q_xy,
    const void* __restrict__ valid_q, const void* __restrict__ valid_map,
    const float* __restrict__ num_valid, const float4* __restrict__ poses,
    const int* __restrict__ bool_is32, float* __restrict__ out) {
  __shared__ float sred[256];
  const int idx = blockIdx.x;  // b*256 + k
  const int tid = threadIdx.x;
  const int b = idx >> 8;
  const int is32 = bool_is32[0];
  const float4 P = poses[idx];
  const float et = expf(temp[0]);
  float acc = 0.f;
  for (int n = tid; n < NQ; n += 256) {
    float2 q = ((const float2*)q_xy)[(size_t)b * NQ + n];
    float px = P.x * q.x - P.y * q.y + P.z;
    float py = P.y * q.x + P.x * q.y + P.w;
    int ii = (int)floorf(px * 2.0f);
    int jj = (int)floorf(py * 2.0f);
    bool inb = (ii >= 0) & (ii < 128) & (jj >= 0) & (jj < 128);
    int ic = min(max(ii, 0), 127), jc = min(max(jj, 0), 127);
    int flat = (ic << 7) + jc;
    bool msk = read_bool(valid_q, b * NQ + n, is32) && inb &&
               read_bool(valid_map, b * IJ + flat, is32);
    if (msk) {
      const float4* fq = (const float4*)(f_q + ((size_t)(b * NQ + n)) * 32);
      const float4* fm = (const float4*)(f_map + ((size_t)(b * IJ + flat)) * 32);
      float dot = 0.f;
#pragma unroll
      for (int j = 0; j < 8; ++j) {
        float4 a = fq[j], cc = fm[j];
        dot = fmaf(a.x, cc.x, dot); dot = fmaf(a.y, cc.y, dot);
        dot = fmaf(a.z, cc.z, dot); dot = fmaf(a.w, cc.w, dot);
      }
      acc += fmaxf(dot, 0.f) * et;
    }
  }
  sred[tid] = acc;
  __syncthreads();
  for (int off = 128; off > 0; off >>= 1) {
    if (tid < off) sred[tid] += sred[tid + off];
    __syncthreads();
  }
  if (tid == 0) out[idx] = sred[0] / num_valid[b];
}

// ---------------------------------------------------------------------------
extern "C" void kernel_launch(void* const* d_in, const int* in_sizes, int n_in,
                              void* d_out, int out_size, void* d_ws,
                              size_t ws_size, hipStream_t stream) {
  const float* f_q = (const float*)d_in[0];
  const float* f_map = (const float*)d_in[1];
  const float* q_xy = (const float*)d_in[2];
  const float* temp = (const float*)d_in[3];
  const void* valid_q = d_in[4];    // numpy bool: width auto-detected
  const void* valid_map = d_in[5];  // numpy bool: width auto-detected
  const int* seedp = (const int*)d_in[6];
  float* out = (float*)d_out;

  char* ws = (char*)d_ws;
  float* num_valid = (float*)(ws + 0);
  int* n_idx = (int*)(ws + 256);
  int* bool_is32 = (int*)(ws + 4352);
  float4* poses = (float4*)(ws + 4608);
  float* row_m = (float*)(ws + 12800);
  float* row_s = (float*)(ws + 16896);
  float* row_th = (float*)(ws + 20992);
  u64* catbest = (u64*)(ws + 25088);
  float* pmax = (float*)(ws + 33280);           // 1024*64 f32 = 256 KB
  float* psum = (float*)(ws + 33280 + 262144);  // 256 KB

  setup_kernel<<<5, 256, 0, stream>>>(valid_q, seedp, num_valid, n_idx,
                                      bool_is32);
  cat1_kernel<<<dim3(NSEG, NGRP), 256, 0, stream>>>(f_q, f_map, temp, n_idx,
                                                    pmax, psum);
  catc_kernel<<<4, 256, 0, stream>>>(pmax, psum, row_m, row_s, row_th, catbest);
  cat2_kernel<<<dim3(NSEG, NGRP), 256, 0, stream>>>(
      f_q, f_map, temp, n_idx, row_m, row_s, row_th, num_valid, seedp, catbest);
  pose_kernel<<<2, 256, 0, stream>>>(q_xy, n_idx, catbest, poses);
  score_kernel<<<NB * KP, 256, 0, stream>>>(f_q, f_map, temp, q_xy, valid_q,
                                            valid_map, num_valid, poses,
                                            bool_is32, out);
}

// Round 13
// 189.278 us; speedup vs baseline: 1.3038x; 1.3038x over previous
//
#include <hip/hip_runtime.h>
#include <hip/hip_bf16.h>
#include <stdint.h>

typedef unsigned int u32;
typedef unsigned long long u64;

#define IJ 16384
#define NQ 1024
#define NB 2
#define KP 256
#define NSEG 64   // ij tiles of 256 cells
#define NGRP 16   // groups of 64 row-instances
#define LMAX 6144 // LDS candidate list cap (expected ~2100 +94 sigma)

// ---------------- Threefry-2x32 (JAX-compatible, 20 rounds) ----------------
__device__ __forceinline__ void tf2x32(u32 k0, u32 k1, u32& x0, u32& x1) {
  u32 kx = k0 ^ k1 ^ 0x1BD11BDAu;
#define TFR(r) { x0 += x1; x1 = (x1 << (r)) | (x1 >> (32 - (r))); x1 ^= x0; }
  x0 += k0; x1 += k1;
  TFR(13) TFR(15) TFR(26) TFR(6)
  x0 += k1; x1 += kx + 1u;
  TFR(17) TFR(29) TFR(16) TFR(24)
  x0 += kx; x1 += k0 + 2u;
  TFR(13) TFR(15) TFR(26) TFR(6)
  x0 += k0; x1 += k1 + 3u;
  TFR(17) TFR(29) TFR(16) TFR(24)
  x0 += k1; x1 += kx + 4u;
  TFR(13) TFR(15) TFR(26) TFR(6)
  x0 += kx; x1 += k0 + 5u;
#undef TFR
}

// threefry_partitionable=True (JAX >= 0.5 default):
// split(key)[i]            = enc_key(0, i)
// random_bits(key,32,…)[i] = w0 ^ w1 of enc_key(hi32(i), lo32(i))
__device__ __forceinline__ void tf_subkey(u32 k0, u32 k1, u32 i, u32& s0, u32& s1) {
  u32 x0 = 0u, x1 = i;
  tf2x32(k0, k1, x0, x1);
  s0 = x0; s1 = x1;
}

__device__ __forceinline__ u32 tf_xorbits(u32 k0, u32 k1, u32 i) {
  u32 x0 = 0u, x1 = i;
  tf2x32(k0, k1, x0, x1);
  return x0 ^ x1;
}

__device__ __forceinline__ void derive_keys(int seed, u32& kq0, u32& kq1,
                                            u32& km0, u32& km1) {
  u32 k0 = 0u;
  u32 k1 = (u32)seed;
  tf_subkey(k0, k1, 0u, kq0, kq1);
  tf_subkey(k0, k1, 1u, km0, km1);
}

// JAX uniform(minval=tiny, maxval=1) -> gumbel. g in [-4.47, 16.64];
// winner bound r >= m - 21.11 => threshold m-25 is safe.
__device__ __forceinline__ float gumbel_from_bits(u32 w) {
  const float tiny = 1.17549435e-38f;
  float fl = __uint_as_float((w >> 9) | 0x3f800000u) - 1.0f;
  float u = fl * (1.0f - tiny) + tiny;
  u = fmaxf(tiny, u);
  return -logf(-logf(u));
}

__device__ __forceinline__ bool read_bool(const void* p, int idx, int is32) {
  return is32 ? (((const int*)p)[idx] != 0)
              : (((const unsigned char*)p)[idx] != 0);
}

// exact categorical value for candidate (bit-identical to R9 expression)
__device__ __forceinline__ float cat_value(float rv, float m, float s, float nv,
                                           u32 km0, u32 km1, u32 idx) {
  u32 w = tf_xorbits(km0, km1, idx);
  float gmb = gumbel_from_bits(w);
  float e = expf(rv - m);
  return logf((e / s) / nv + 1e-20f) + gmb;
}

__device__ __forceinline__ u64 pack_key(float v, int f) {
  u32 vb = __float_as_uint(v);
  u32 srt = (vb & 0x80000000u) ? ~vb : (vb | 0x80000000u);
  return ((u64)srt << 32) | (u64)(0xFFFFFFFFu - (u32)f);
}

// ---------------- setup: n_idx, bool-width detect, num_valid ---------------
__global__ void setup_kernel(const void* __restrict__ valid_q,
                             const int* __restrict__ seedp,
                             float* __restrict__ num_valid,
                             int* __restrict__ n_idx,
                             int* __restrict__ bool_is32) {
  __shared__ int sred[256];
  __shared__ int is32_s;
  const int blk = blockIdx.x, tid = threadIdx.x;
  if (blk < 4) {
    // randint(kq,(2,512),0,1024): k1,k2 = split(kq); multiplier = 0
    int s = blk * 256 + tid;  // 0..1023
    u32 kq0, kq1, km0, km1;
    derive_keys(seedp[0], kq0, kq1, km0, km1);
    u32 l0, l1;  // k2 = enc(kq, (0,1))
    tf_subkey(kq0, kq1, 1u, l0, l1);
    u32 w = tf_xorbits(l0, l1, (u32)s);
    n_idx[s] = (int)(w & 1023u);
  } else {
    const unsigned char* vb = (const unsigned char*)valid_q;
    int ones = 0;
    for (int i = tid; i < 2048; i += 256) ones += (vb[i] == 1) ? 1 : 0;
    sred[tid] = ones;
    __syncthreads();
    for (int off = 128; off > 0; off >>= 1) {
      if (tid < off) sred[tid] += sred[tid + off];
      __syncthreads();
    }
    if (tid == 0) {
      is32_s = (sred[0] < 1152) ? 1 : 0;
      bool_is32[0] = is32_s;
    }
    __syncthreads();
    const int is32 = is32_s;
    for (int b = 0; b < 2; ++b) {
      int acc = 0;
      for (int i = tid; i < NQ; i += 256)
        acc += read_bool(valid_q, b * NQ + i, is32) ? 1 : 0;
      sred[tid] = acc;
      __syncthreads();
      for (int off = 128; off > 0; off >>= 1) {
        if (tid < off) sred[tid] += sred[tid + off];
        __syncthreads();
      }
      if (tid == 0) {
        float nv = (float)sred[0];
        num_valid[b] = nv < 1.f ? 1.f : nv;
      }
      __syncthreads();
    }
  }
}

// Shared micro-kernel (R9/R11 staging: coalesced global reads, transposed
// LDS writes): 64 gathered rows x 256 cells, d-major LDS, 8x8/thread.
// As/Bs contents and the d-ascending fmaf chain identical to R9 ->
// acc is bit-identical.
#define GEMM_TILE_BODY                                                        \
  for (int q = tid; q < 512; q += 256) {                                      \
    int row = q >> 3, dg = (q & 7) << 2;                                      \
    int n = n_idx[t0 + row];                                                  \
    const float4 v = *(const float4*)(f_q + ((size_t)(b * NQ + n)) * 32 + dg);\
    As[dg][row] = v.x; As[dg + 1][row] = v.y;                                 \
    As[dg + 2][row] = v.z; As[dg + 3][row] = v.w;                             \
  }                                                                           \
  {                                                                           \
    const float4* gB = (const float4*)(f_map + ((size_t)b * IJ + ij0) * 32);  \
    for (int q = tid; q < 2048; q += 256) {                                   \
      float4 v = gB[q];                                                       \
      int jj = q >> 3, dg = (q & 7) << 2;                                     \
      Bs[dg][jj] = v.x; Bs[dg + 1][jj] = v.y;                                 \
      Bs[dg + 2][jj] = v.z; Bs[dg + 3][jj] = v.w;                             \
    }                                                                         \
  }                                                                           \
  __syncthreads();                                                            \
  const int ty = tid >> 5, tx = tid & 31;                                     \
  float acc[2][2][4][4] = {};                                                 \
  _Pragma("unroll 8")                                                         \
  for (int d = 0; d < 32; ++d) {                                              \
    float4 a0 = *(const float4*)&As[d][ty << 2];                              \
    float4 a1 = *(const float4*)&As[d][(ty << 2) + 32];                       \
    float4 b0 = *(const float4*)&Bs[d][tx << 2];                              \
    float4 b1 = *(const float4*)&Bs[d][(tx << 2) + 128];                      \
    float av[2][4] = {{a0.x, a0.y, a0.z, a0.w}, {a1.x, a1.y, a1.z, a1.w}};    \
    float bv[2][4] = {{b0.x, b0.y, b0.z, b0.w}, {b1.x, b1.y, b1.z, b1.w}};    \
    _Pragma("unroll")                                                         \
    for (int rg = 0; rg < 2; ++rg)                                            \
      _Pragma("unroll")                                                       \
      for (int cg = 0; cg < 2; ++cg)                                          \
        _Pragma("unroll")                                                     \
        for (int r = 0; r < 4; ++r)                                           \
          _Pragma("unroll")                                                   \
          for (int c = 0; c < 4; ++c)                                         \
            acc[rg][cg][r][c] = fmaf(av[rg][r], bv[cg][c], acc[rg][cg][r][c]);\
  }

// ---------------- cat1: per-(instance,seg) row max + sum(e^r) --------------
__global__ __launch_bounds__(256) void cat1_kernel(
    const float* __restrict__ f_q, const float* __restrict__ f_map,
    const float* __restrict__ temp, const int* __restrict__ n_idx,
    float* __restrict__ pmax, float* __restrict__ psum) {
  __shared__ float As[32][64];
  __shared__ float Bs[32][256];
  const int tid = threadIdx.x;
  const int g = blockIdx.y;
  const int t0 = g * 64;
  const int b = t0 >> 9;
  const int ij0 = blockIdx.x * 256;

  GEMM_TILE_BODY

  const float et = expf(temp[0]);
#pragma unroll
  for (int rg = 0; rg < 2; ++rg) {
#pragma unroll
    for (int r = 0; r < 4; ++r) {
      const int lrow = rg * 32 + (ty << 2) + r;
      float rm = 0.f, se = 0.f;
#pragma unroll
      for (int cg = 0; cg < 2; ++cg) {
        float o0 = fmaxf(acc[rg][cg][r][0], 0.f) * et;
        float o1 = fmaxf(acc[rg][cg][r][1], 0.f) * et;
        float o2 = fmaxf(acc[rg][cg][r][2], 0.f) * et;
        float o3 = fmaxf(acc[rg][cg][r][3], 0.f) * et;
        rm = fmaxf(rm, fmaxf(fmaxf(o0, o1), fmaxf(o2, o3)));
        se += expf(o0); se += expf(o1); se += expf(o2); se += expf(o3);
      }
#pragma unroll
      for (int off = 16; off > 0; off >>= 1) {
        se += __shfl_down(se, off, 32);
        rm = fmaxf(rm, __shfl_down(rm, off, 32));
      }
      if (tx == 0) {
        pmax[(size_t)(t0 + lrow) * NSEG + blockIdx.x] = rm;
        psum[(size_t)(t0 + lrow) * NSEG + blockIdx.x] = se;
      }
    }
  }
}

// ---------------- combine: m, s = Σe^r · e^-m, th = m-25; zero catbest -----
__global__ void catc_kernel(const float* __restrict__ pmax,
                            const float* __restrict__ psum,
                            float* __restrict__ row_m, float* __restrict__ row_s,
                            float* __restrict__ row_th,
                            u64* __restrict__ catbest) {
  const int t = blockIdx.x * 256 + threadIdx.x;
  if (t >= NB * 512) return;
  float m = 0.f, ss = 0.f;
#pragma unroll
  for (int s = 0; s < NSEG; ++s) m = fmaxf(m, pmax[(size_t)t * NSEG + s]);
#pragma unroll
  for (int s = 0; s < NSEG; ++s) ss += psum[(size_t)t * NSEG + s];
  row_m[t] = m;
  row_s[t] = ss * expf(-m);
  row_th[t] = m - 25.0f;
  catbest[t] = 0ULL;
}

// ---------------- cat2: recompute tile, LDS (rv,idx) list, argmax ----------
// Phase 1: ballot-aggregated push of candidates (rv > th) into LDS arrays
// candr (f32 rv, exact bits) + candm (packed u16). Slot >= LMAX (never at
// ~2100 expected vs 6144 cap) evals inline immediately — exact either way,
// the u64 (max v, tie->min f) lattice is order-independent.
// Phase 2: dense eval, 2 LDS reads per candidate.
__global__ __launch_bounds__(256) void cat2_kernel(
    const float* __restrict__ f_q, const float* __restrict__ f_map,
    const float* __restrict__ temp, const int* __restrict__ n_idx,
    const float* __restrict__ row_m, const float* __restrict__ row_s,
    const float* __restrict__ row_th, const float* __restrict__ num_valid,
    const int* __restrict__ seedp, u64* __restrict__ catbest) {
  __shared__ float As[32][64];
  __shared__ float Bs[32][256];
  __shared__ float candr[LMAX];
  __shared__ unsigned short candm[LMAX];
  __shared__ float m_s[64], s_s[64], th_s[64];
  __shared__ int ccount;
  __shared__ u32 keys2[2];
  __shared__ u64 best[64];
  const int tid = threadIdx.x;
  const int g = blockIdx.y;
  const int t0 = g * 64;
  const int b = t0 >> 9;
  const int ij0 = blockIdx.x * 256;

  if (tid == 0) {
    u32 kq0, kq1, km0_, km1_;
    derive_keys(seedp[0], kq0, kq1, km0_, km1_);
    keys2[0] = km0_; keys2[1] = km1_;
    ccount = 0;
  }
  if (tid < 64) {
    best[tid] = 0ULL;
    m_s[tid] = row_m[t0 + tid];
    s_s[tid] = row_s[t0 + tid];
    th_s[tid] = row_th[t0 + tid];
  }

  GEMM_TILE_BODY

  const float et = expf(temp[0]);
  const float nv = num_valid[b];
  const u32 km0 = keys2[0], km1 = keys2[1];
  const int lane = tid & 63;

  // phase 1: ballot-aggregated candidate push
#pragma unroll
  for (int rg = 0; rg < 2; ++rg) {
#pragma unroll
    for (int r = 0; r < 4; ++r) {
      const int lrow = rg * 32 + (ty << 2) + r;
      const float th = th_s[lrow];
#pragma unroll
      for (int cg = 0; cg < 2; ++cg) {
#pragma unroll
        for (int c = 0; c < 4; ++c) {
          float rv = fmaxf(acc[rg][cg][r][c], 0.f) * et;
          bool active = rv > th;
          u64 mask = __ballot(active);
          if (mask) {
            int leader = __ffsll((u64)mask) - 1;
            int base = 0;
            if (lane == leader) base = atomicAdd(&ccount, (int)__popcll(mask));
            base = __shfl(base, leader);
            if (active) {
              int slot = base + (int)__popcll(mask & ((1ULL << lane) - 1ULL));
              int cell = cg * 128 + (tx << 2) + c;
              if (slot < LMAX) {
                candr[slot] = rv;
                candm[slot] = (unsigned short)((lrow << 8) | cell);
              } else {  // overflow (never expected): eval inline, bit-exact
                int t = t0 + lrow;
                int f = ij0 + cell;
                u32 idx = (u32)((t & 511) * IJ + f) + ((u32)b << 23);
                float v = cat_value(rv, m_s[lrow], s_s[lrow], nv, km0, km1, idx);
                atomicMax(&best[lrow], pack_key(v, f));
              }
            }
          }
        }
      }
    }
  }
  __syncthreads();

  // phase 2: dense eval over the list
  const int cnt = min(ccount, LMAX);
  for (int ci = tid; ci < cnt; ci += 256) {
    float rv = candr[ci];
    int mm = (int)candm[ci];
    int lrow = mm >> 8, cell = mm & 255;
    int t = t0 + lrow;
    int f = ij0 + cell;
    u32 idx = (u32)((t & 511) * IJ + f) + ((u32)b << 23);
    float v = cat_value(rv, m_s[lrow], s_s[lrow], nv, km0, km1, idx);
    atomicMax(&best[lrow], pack_key(v, f));
  }
  __syncthreads();
  if (tid < 64 && best[tid] != 0ULL) atomicMax(&catbest[t0 + tid], best[tid]);
}

// ---------------- pose hypotheses (R, t); m_flat decoded from catbest ------
__global__ void pose_kernel(const float* __restrict__ q_xy,
                            const int* __restrict__ n_idx,
                            const u64* __restrict__ catbest,
                            float4* __restrict__ poses) {
  const int idx = blockIdx.x * 256 + threadIdx.x;  // 0..511
  if (idx >= NB * KP) return;
  const int b = idx >> 8, k = idx & 255;
  const int t0 = b * 512 + 2 * k, t1 = t0 + 1;
  const int na = n_idx[t0], nb = n_idx[t1];
  const float2 q0 = ((const float2*)q_xy)[(size_t)b * NQ + na];
  const float2 q1 = ((const float2*)q_xy)[(size_t)b * NQ + nb];
  const int ma = (int)(0xFFFFFFFFu - (u32)(catbest[t0] & 0xFFFFFFFFull));
  const int mb = (int)(0xFFFFFFFFu - (u32)(catbest[t1] & 0xFFFFFFFFull));
  const float m0x = ((float)(ma >> 7) + 0.5f) * 0.5f;
  const float m0y = ((float)(ma & 127) + 0.5f) * 0.5f;
  const float m1x = ((float)(mb >> 7) + 0.5f) * 0.5f;
  const float m1y = ((float)(mb & 127) + 0.5f) * 0.5f;
  const float dqx = q1.x - q0.x, dqy = q1.y - q0.y;
  const float dmx = m1x - m0x, dmy = m1y - m0y;
  const float theta = atan2f(dmy, dmx) - atan2f(dqy, dqx);
  const float c = cosf(theta), s = sinf(theta);
  const float tx = m0x - (c * q0.x - s * q0.y);
  const float ty = m0y - (s * q0.x + c * q0.y);
  poses[idx] = make_float4(c, s, tx, ty);
}

// ---------------- score: recompute gathered sim values on the fly ----------
__global__ __launch_bounds__(256) void score_kernel(
    const float* __restrict__ f_q, const float* __restrict__ f_map,
    const float* __restrict__ temp, const float* __restrict__ q_xy,
    const void* __restrict__ valid_q, const void* __restrict__ valid_map,
    const float* __restrict__ num_valid, const float4* __restrict__ poses,
    const int* __restrict__ bool_is32, float* __restrict__ out) {
  __shared__ float sred[256];
  const int idx = blockIdx.x;  // b*256 + k
  const int tid = threadIdx.x;
  const int b = idx >> 8;
  const int is32 = bool_is32[0];
  const float4 P = poses[idx];
  const float et = expf(temp[0]);
  float acc = 0.f;
  for (int n = tid; n < NQ; n += 256) {
    float2 q = ((const float2*)q_xy)[(size_t)b * NQ + n];
    float px = P.x * q.x - P.y * q.y + P.z;
    float py = P.y * q.x + P.x * q.y + P.w;
    int ii = (int)floorf(px * 2.0f);
    int jj = (int)floorf(py * 2.0f);
    bool inb = (ii >= 0) & (ii < 128) & (jj >= 0) & (jj < 128);
    int ic = min(max(ii, 0), 127), jc = min(max(jj, 0), 127);
    int flat = (ic << 7) + jc;
    bool msk = read_bool(valid_q, b * NQ + n, is32) && inb &&
               read_bool(valid_map, b * IJ + flat, is32);
    if (msk) {
      const float4* fq = (const float4*)(f_q + ((size_t)(b * NQ + n)) * 32);
      const float4* fm = (const float4*)(f_map + ((size_t)(b * IJ + flat)) * 32);
      float dot = 0.f;
#pragma unroll
      for (int j = 0; j < 8; ++j) {
        float4 a = fq[j], cc = fm[j];
        dot = fmaf(a.x, cc.x, dot); dot = fmaf(a.y, cc.y, dot);
        dot = fmaf(a.z, cc.z, dot); dot = fmaf(a.w, cc.w, dot);
      }
      acc += fmaxf(dot, 0.f) * et;
    }
  }
  sred[tid] = acc;
  __syncthreads();
  for (int off = 128; off > 0; off >>= 1) {
    if (tid < off) sred[tid] += sred[tid + off];
    __syncthreads();
  }
  if (tid == 0) out[idx] = sred[0] / num_valid[b];
}

// ---------------------------------------------------------------------------
extern "C" void kernel_launch(void* const* d_in, const int* in_sizes, int n_in,
                              void* d_out, int out_size, void* d_ws,
                              size_t ws_size, hipStream_t stream) {
  const float* f_q = (const float*)d_in[0];
  const float* f_map = (const float*)d_in[1];
  const float* q_xy = (const float*)d_in[2];
  const float* temp = (const float*)d_in[3];
  const void* valid_q = d_in[4];    // numpy bool: width auto-detected
  const void* valid_map = d_in[5];  // numpy bool: width auto-detected
  const int* seedp = (const int*)d_in[6];
  float* out = (float*)d_out;

  char* ws = (char*)d_ws;
  float* num_valid = (float*)(ws + 0);
  int* n_idx = (int*)(ws + 256);
  int* bool_is32 = (int*)(ws + 4352);
  float4* poses = (float4*)(ws + 4608);
  float* row_m = (float*)(ws + 12800);
  float* row_s = (float*)(ws + 16896);
  float* row_th = (float*)(ws + 20992);
  u64* catbest = (u64*)(ws + 25088);
  float* pmax = (float*)(ws + 33280);           // 1024*64 f32 = 256 KB
  float* psum = (float*)(ws + 33280 + 262144);  // 256 KB

  setup_kernel<<<5, 256, 0, stream>>>(valid_q, seedp, num_valid, n_idx,
                                      bool_is32);
  cat1_kernel<<<dim3(NSEG, NGRP), 256, 0, stream>>>(f_q, f_map, temp, n_idx,
                                                    pmax, psum);
  catc_kernel<<<4, 256, 0, stream>>>(pmax, psum, row_m, row_s, row_th, catbest);
  cat2_kernel<<<dim3(NSEG, NGRP), 256, 0, stream>>>(
      f_q, f_map, temp, n_idx, row_m, row_s, row_th, num_valid, seedp, catbest);
  pose_kernel<<<2, 256, 0, stream>>>(q_xy, n_idx, catbest, poses);
  score_kernel<<<NB * KP, 256, 0, stream>>>(f_q, f_map, temp, q_xy, valid_q,
                                            valid_map, num_valid, poses,
                                            bool_is32, out);
}

// Round 14
// 183.658 us; speedup vs baseline: 1.3437x; 1.0306x over previous
//
#include <hip/hip_runtime.h>
#include <hip/hip_bf16.h>
#include <stdint.h>

typedef unsigned int u32;
typedef unsigned long long u64;

#define IJ 16384
#define NQ 1024
#define NB 2
#define KP 256
#define NSEG 128  // ij tiles of 128 cells
#define NGRP 8    // groups of 128 row-instances
#define LMAX 2560 // LDS candidate list cap (expected ~1400-2000; overflow -> exact inline fallback)

// ---------------- Threefry-2x32 (JAX-compatible, 20 rounds) ----------------
__device__ __forceinline__ void tf2x32(u32 k0, u32 k1, u32& x0, u32& x1) {
  u32 kx = k0 ^ k1 ^ 0x1BD11BDAu;
#define TFR(r) { x0 += x1; x1 = (x1 << (r)) | (x1 >> (32 - (r))); x1 ^= x0; }
  x0 += k0; x1 += k1;
  TFR(13) TFR(15) TFR(26) TFR(6)
  x0 += k1; x1 += kx + 1u;
  TFR(17) TFR(29) TFR(16) TFR(24)
  x0 += kx; x1 += k0 + 2u;
  TFR(13) TFR(15) TFR(26) TFR(6)
  x0 += k0; x1 += k1 + 3u;
  TFR(17) TFR(29) TFR(16) TFR(24)
  x0 += k1; x1 += kx + 4u;
  TFR(13) TFR(15) TFR(26) TFR(6)
  x0 += kx; x1 += k0 + 5u;
#undef TFR
}

// threefry_partitionable=True (JAX >= 0.5 default):
// split(key)[i]            = enc_key(0, i)
// random_bits(key,32,…)[i] = w0 ^ w1 of enc_key(hi32(i), lo32(i))
__device__ __forceinline__ void tf_subkey(u32 k0, u32 k1, u32 i, u32& s0, u32& s1) {
  u32 x0 = 0u, x1 = i;
  tf2x32(k0, k1, x0, x1);
  s0 = x0; s1 = x1;
}

__device__ __forceinline__ u32 tf_xorbits(u32 k0, u32 k1, u32 i) {
  u32 x0 = 0u, x1 = i;
  tf2x32(k0, k1, x0, x1);
  return x0 ^ x1;
}

__device__ __forceinline__ void derive_keys(int seed, u32& kq0, u32& kq1,
                                            u32& km0, u32& km1) {
  u32 k0 = 0u;
  u32 k1 = (u32)seed;
  tf_subkey(k0, k1, 0u, kq0, kq1);
  tf_subkey(k0, k1, 1u, km0, km1);
}

// JAX uniform(minval=tiny, maxval=1) -> gumbel. g in [-4.47, 16.64];
// winner bound r >= m - 21.11 => threshold m-25 is safe.
__device__ __forceinline__ float gumbel_from_bits(u32 w) {
  const float tiny = 1.17549435e-38f;
  float fl = __uint_as_float((w >> 9) | 0x3f800000u) - 1.0f;
  float u = fl * (1.0f - tiny) + tiny;
  u = fmaxf(tiny, u);
  return -logf(-logf(u));
}

__device__ __forceinline__ bool read_bool(const void* p, int idx, int is32) {
  return is32 ? (((const int*)p)[idx] != 0)
              : (((const unsigned char*)p)[idx] != 0);
}

// exact categorical value for candidate (bit-identical to R9 expression)
__device__ __forceinline__ float cat_value(float rv, float m, float s, float nv,
                                           u32 km0, u32 km1, u32 idx) {
  u32 w = tf_xorbits(km0, km1, idx);
  float gmb = gumbel_from_bits(w);
  float e = expf(rv - m);
  return logf((e / s) / nv + 1e-20f) + gmb;
}

__device__ __forceinline__ u64 pack_key(float v, int f) {
  u32 vb = __float_as_uint(v);
  u32 srt = (vb & 0x80000000u) ? ~vb : (vb | 0x80000000u);
  return ((u64)srt << 32) | (u64)(0xFFFFFFFFu - (u32)f);
}

// ---------------- setup: n_idx, bool-width detect, num_valid ---------------
__global__ void setup_kernel(const void* __restrict__ valid_q,
                             const int* __restrict__ seedp,
                             float* __restrict__ num_valid,
                             int* __restrict__ n_idx,
                             int* __restrict__ bool_is32) {
  __shared__ int sred[256];
  __shared__ int is32_s;
  const int blk = blockIdx.x, tid = threadIdx.x;
  if (blk < 4) {
    // randint(kq,(2,512),0,1024): k1,k2 = split(kq); multiplier = 0
    int s = blk * 256 + tid;  // 0..1023
    u32 kq0, kq1, km0, km1;
    derive_keys(seedp[0], kq0, kq1, km0, km1);
    u32 l0, l1;  // k2 = enc(kq, (0,1))
    tf_subkey(kq0, kq1, 1u, l0, l1);
    u32 w = tf_xorbits(l0, l1, (u32)s);
    n_idx[s] = (int)(w & 1023u);
  } else {
    const unsigned char* vb = (const unsigned char*)valid_q;
    int ones = 0;
    for (int i = tid; i < 2048; i += 256) ones += (vb[i] == 1) ? 1 : 0;
    sred[tid] = ones;
    __syncthreads();
    for (int off = 128; off > 0; off >>= 1) {
      if (tid < off) sred[tid] += sred[tid + off];
      __syncthreads();
    }
    if (tid == 0) {
      is32_s = (sred[0] < 1152) ? 1 : 0;
      bool_is32[0] = is32_s;
    }
    __syncthreads();
    const int is32 = is32_s;
    for (int b = 0; b < 2; ++b) {
      int acc = 0;
      for (int i = tid; i < NQ; i += 256)
        acc += read_bool(valid_q, b * NQ + i, is32) ? 1 : 0;
      sred[tid] = acc;
      __syncthreads();
      for (int off = 128; off > 0; off >>= 1) {
        if (tid < off) sred[tid] += sred[tid + off];
        __syncthreads();
      }
      if (tid == 0) {
        float nv = (float)sred[0];
        num_valid[b] = nv < 1.f ? 1.f : nv;
      }
      __syncthreads();
    }
  }
}

// Shared micro-kernel: 128 gathered rows x 128 cells, d-major LDS, 8x8/thread.
// A staged lane-per-row (conflict-free writes); B staged with coalesced global
// reads and XOR-swizzled LDS columns: element (d,j) lives at column
// 4*((j>>2) ^ (d>>2)) + (j&3)  -> write banks distinct, reads stay aligned
// b128. The per-(row,cell) fmaf chain is d-ascending 0..31 -> acc values are
// bit-identical to R9/R13.
#define GEMM_TILE_BODY                                                        \
  _Pragma("unroll")                                                           \
  for (int k = 0; k < 4; ++k) {                                               \
    int q = tid + k * 256;                                                    \
    int row = q & 127, ch = q >> 7;                                           \
    int n = n_idx[t0 + row];                                                  \
    const float4 v = *(const float4*)(f_q + ((size_t)(b * NQ + n)) * 32 +     \
                                      ch * 4);                                \
    As[ch * 4 + 0][row] = v.x; As[ch * 4 + 1][row] = v.y;                     \
    As[ch * 4 + 2][row] = v.z; As[ch * 4 + 3][row] = v.w;                     \
  }                                                                           \
  _Pragma("unroll")                                                           \
  for (int k = 0; k < 4; ++k) {                                               \
    int q = tid + k * 256;                                                    \
    int jj = q >> 3, dg = (q & 7) << 2;                                       \
    const float4 v = *(const float4*)(f_map +                                 \
        ((size_t)(b * IJ + ij0 + jj)) * 32 + dg);                             \
    int col = 4 * ((jj >> 2) ^ (q & 7)) + (jj & 3);                           \
    Bs[dg + 0][col] = v.x; Bs[dg + 1][col] = v.y;                             \
    Bs[dg + 2][col] = v.z; Bs[dg + 3][col] = v.w;                             \
  }                                                                           \
  __syncthreads();                                                            \
  const int ty = tid >> 4, tx = tid & 15;                                     \
  float acc[8][8] = {};                                                       \
  _Pragma("unroll 4")                                                         \
  for (int d = 0; d < 32; ++d) {                                              \
    const int sd = (d >> 2) & 7;                                              \
    float4 a0 = *(const float4*)&As[d][ty * 8];                               \
    float4 a1 = *(const float4*)&As[d][ty * 8 + 4];                           \
    float4 b0 = *(const float4*)&Bs[d][4 * ((tx * 2) ^ sd)];                  \
    float4 b1 = *(const float4*)&Bs[d][4 * ((tx * 2 + 1) ^ sd)];              \
    float av[8] = {a0.x, a0.y, a0.z, a0.w, a1.x, a1.y, a1.z, a1.w};           \
    float bv[8] = {b0.x, b0.y, b0.z, b0.w, b1.x, b1.y, b1.z, b1.w};           \
    _Pragma("unroll")                                                         \
    for (int r = 0; r < 8; ++r)                                               \
      _Pragma("unroll")                                                       \
      for (int c = 0; c < 8; ++c)                                             \
        acc[r][c] = fmaf(av[r], bv[c], acc[r][c]);                            \
  }

// ---------------- cat1: per-(instance,seg) row max + sum(e^r) --------------
__global__ __launch_bounds__(256) void cat1_kernel(
    const float* __restrict__ f_q, const float* __restrict__ f_map,
    const float* __restrict__ temp, const int* __restrict__ n_idx,
    float* __restrict__ pmax, float* __restrict__ psum) {
  __shared__ float As[32][128];
  __shared__ float Bs[32][128];
  const int tid = threadIdx.x;
  const int t0 = blockIdx.y * 128;
  const int b = t0 >> 9;
  const int ij0 = blockIdx.x * 128;

  GEMM_TILE_BODY

  const float et = expf(temp[0]);
#pragma unroll
  for (int r = 0; r < 8; ++r) {
    const int lrow = ty * 8 + r;
    float rm = 0.f, se = 0.f;
#pragma unroll
    for (int c = 0; c < 8; ++c) {
      float o = fmaxf(acc[r][c], 0.f) * et;
      rm = fmaxf(rm, o);
      se += expf(o);
    }
#pragma unroll
    for (int off = 8; off > 0; off >>= 1) {
      se += __shfl_down(se, off, 16);
      rm = fmaxf(rm, __shfl_down(rm, off, 16));
    }
    if (tx == 0) {
      pmax[(size_t)(t0 + lrow) * NSEG + blockIdx.x] = rm;
      psum[(size_t)(t0 + lrow) * NSEG + blockIdx.x] = se;
    }
  }
}

// ---------------- combine (block per instance): m, s, th; zero outputs -----
__global__ __launch_bounds__(128) void catc_kernel(
    const float* __restrict__ pmax, const float* __restrict__ psum,
    float* __restrict__ row_m, float* __restrict__ row_s,
    float* __restrict__ row_th, u64* __restrict__ catbest,
    float* __restrict__ out) {
  __shared__ float red[128];
  const int t = blockIdx.x;  // 0..1023
  const int tid = threadIdx.x;
  float pm = pmax[(size_t)t * NSEG + tid];
  float ps = psum[(size_t)t * NSEG + tid];
  red[tid] = pm;
  __syncthreads();
  for (int off = 64; off > 0; off >>= 1) {
    if (tid < off) red[tid] = fmaxf(red[tid], red[tid + off]);
    __syncthreads();
  }
  const float m = red[0];
  __syncthreads();
  red[tid] = ps;
  __syncthreads();
  for (int off = 64; off > 0; off >>= 1) {
    if (tid < off) red[tid] += red[tid + off];
    __syncthreads();
  }
  if (tid == 0) {
    row_m[t] = m;
    row_s[t] = red[0] * expf(-m);
    row_th[t] = m - 25.0f;
    catbest[t] = 0ULL;
  }
  if (t < NB * KP && tid == 1) out[t] = 0.f;
}

// ---------------- cat2: recompute tile, LDS (rv,idx) list, argmax ----------
// Ballot-aggregated push of candidates (rv > th) into candr/candm; slot >=
// LMAX evals inline immediately (exact either way — the u64 (max v,
// tie->min f) lattice is order-independent). Phase 2: dense eval.
__global__ __launch_bounds__(256) void cat2_kernel(
    const float* __restrict__ f_q, const float* __restrict__ f_map,
    const float* __restrict__ temp, const int* __restrict__ n_idx,
    const float* __restrict__ row_m, const float* __restrict__ row_s,
    const float* __restrict__ row_th, const float* __restrict__ num_valid,
    const int* __restrict__ seedp, u64* __restrict__ catbest) {
  __shared__ float As[32][128];
  __shared__ float Bs[32][128];
  __shared__ float candr[LMAX];
  __shared__ unsigned short candm[LMAX];
  __shared__ float m_s[128], s_s[128], th_s[128];
  __shared__ int ccount;
  __shared__ u32 keys2[2];
  __shared__ u64 best[128];
  const int tid = threadIdx.x;
  const int t0 = blockIdx.y * 128;
  const int b = t0 >> 9;
  const int ij0 = blockIdx.x * 128;

  if (tid == 0) {
    u32 kq0, kq1, km0_, km1_;
    derive_keys(seedp[0], kq0, kq1, km0_, km1_);
    keys2[0] = km0_; keys2[1] = km1_;
    ccount = 0;
  }
  if (tid < 128) {
    best[tid] = 0ULL;
    m_s[tid] = row_m[t0 + tid];
    s_s[tid] = row_s[t0 + tid];
    th_s[tid] = row_th[t0 + tid];
  }

  GEMM_TILE_BODY

  const float et = expf(temp[0]);
  const float nv = num_valid[b];
  const u32 km0 = keys2[0], km1 = keys2[1];
  const int lane = tid & 63;

  // phase 1: ballot-aggregated candidate push
#pragma unroll
  for (int r = 0; r < 8; ++r) {
    const int lrow = ty * 8 + r;
    const float th = th_s[lrow];
#pragma unroll
    for (int c = 0; c < 8; ++c) {
      float rv = fmaxf(acc[r][c], 0.f) * et;
      bool active = rv > th;
      u64 mask = __ballot(active);
      if (mask) {
        int leader = __ffsll((u64)mask) - 1;
        int base = 0;
        if (lane == leader) base = atomicAdd(&ccount, (int)__popcll(mask));
        base = __shfl(base, leader);
        if (active) {
          int slot = base + (int)__popcll(mask & ((1ULL << lane) - 1ULL));
          int cell = tx * 8 + c;
          if (slot < LMAX) {
            candr[slot] = rv;
            candm[slot] = (unsigned short)((lrow << 7) | cell);
          } else {  // rare overflow: eval inline, bit-exact
            int t = t0 + lrow;
            int f = ij0 + cell;
            u32 idx = (u32)((t & 511) * IJ + f) + ((u32)b << 23);
            float v = cat_value(rv, m_s[lrow], s_s[lrow], nv, km0, km1, idx);
            atomicMax(&best[lrow], pack_key(v, f));
          }
        }
      }
    }
  }
  __syncthreads();

  // phase 2: dense eval over the list
  const int cnt = min(ccount, LMAX);
  for (int ci = tid; ci < cnt; ci += 256) {
    float rv = candr[ci];
    int mm = (int)candm[ci];
    int lrow = mm >> 7, cell = mm & 127;
    int t = t0 + lrow;
    int f = ij0 + cell;
    u32 idx = (u32)((t & 511) * IJ + f) + ((u32)b << 23);
    float v = cat_value(rv, m_s[lrow], s_s[lrow], nv, km0, km1, idx);
    atomicMax(&best[lrow], pack_key(v, f));
  }
  __syncthreads();
  if (tid < 128 && best[tid] != 0ULL) atomicMax(&catbest[t0 + tid], best[tid]);
}

// ---------------- pose hypotheses (R, t); m_flat decoded from catbest ------
__global__ void pose_kernel(const float* __restrict__ q_xy,
                            const int* __restrict__ n_idx,
                            const u64* __restrict__ catbest,
                            float4* __restrict__ poses) {
  const int idx = blockIdx.x * 256 + threadIdx.x;  // 0..511
  if (idx >= NB * KP) return;
  const int b = idx >> 8, k = idx & 255;
  const int t0 = b * 512 + 2 * k, t1 = t0 + 1;
  const int na = n_idx[t0], nb = n_idx[t1];
  const float2 q0 = ((const float2*)q_xy)[(size_t)b * NQ + na];
  const float2 q1 = ((const float2*)q_xy)[(size_t)b * NQ + nb];
  const int ma = (int)(0xFFFFFFFFu - (u32)(catbest[t0] & 0xFFFFFFFFull));
  const int mb = (int)(0xFFFFFFFFu - (u32)(catbest[t1] & 0xFFFFFFFFull));
  const float m0x = ((float)(ma >> 7) + 0.5f) * 0.5f;
  const float m0y = ((float)(ma & 127) + 0.5f) * 0.5f;
  const float m1x = ((float)(mb >> 7) + 0.5f) * 0.5f;
  const float m1y = ((float)(mb & 127) + 0.5f) * 0.5f;
  const float dqx = q1.x - q0.x, dqy = q1.y - q0.y;
  const float dmx = m1x - m0x, dmy = m1y - m0y;
  const float theta = atan2f(dmy, dmx) - atan2f(dqy, dqx);
  const float c = cosf(theta), s = sinf(theta);
  const float tx = m0x - (c * q0.x - s * q0.y);
  const float ty = m0y - (s * q0.x + c * q0.y);
  poses[idx] = make_float4(c, s, tx, ty);
}

// ---------------- score: 4 partial blocks per pose, atomic combine ---------
__global__ __launch_bounds__(256) void score_kernel(
    const float* __restrict__ f_q, const float* __restrict__ f_map,
    const float* __restrict__ temp, const float* __restrict__ q_xy,
    const void* __restrict__ valid_q, const void* __restrict__ valid_map,
    const float* __restrict__ num_valid, const float4* __restrict__ poses,
    const int* __restrict__ bool_is32, float* __restrict__ out) {
  __shared__ float sred[256];
  const int idx = blockIdx.y;  // b*256 + k
  const int tid = threadIdx.x;
  const int b = idx >> 8;
  const int is32 = bool_is32[0];
  const float4 P = poses[idx];
  const float et = expf(temp[0]);
  const int n = blockIdx.x * 256 + tid;  // one n per thread
  float acc = 0.f;
  {
    float2 q = ((const float2*)q_xy)[(size_t)b * NQ + n];
    float px = P.x * q.x - P.y * q.y + P.z;
    float py = P.y * q.x + P.x * q.y + P.w;
    int ii = (int)floorf(px * 2.0f);
    int jj = (int)floorf(py * 2.0f);
    bool inb = (ii >= 0) & (ii < 128) & (jj >= 0) & (jj < 128);
    int ic = min(max(ii, 0), 127), jc = min(max(jj, 0), 127);
    int flat = (ic << 7) + jc;
    bool msk = read_bool(valid_q, b * NQ + n, is32) && inb &&
               read_bool(valid_map, b * IJ + flat, is32);
    if (msk) {
      const float4* fq = (const float4*)(f_q + ((size_t)(b * NQ + n)) * 32);
      const float4* fm = (const float4*)(f_map + ((size_t)(b * IJ + flat)) * 32);
      float dot = 0.f;
#pragma unroll
      for (int j = 0; j < 8; ++j) {
        float4 a = fq[j], cc = fm[j];
        dot = fmaf(a.x, cc.x, dot); dot = fmaf(a.y, cc.y, dot);
        dot = fmaf(a.z, cc.z, dot); dot = fmaf(a.w, cc.w, dot);
      }
      acc = fmaxf(dot, 0.f) * et;
    }
  }
  sred[tid] = acc;
  __syncthreads();
  for (int off = 128; off > 0; off >>= 1) {
    if (tid < off) sred[tid] += sred[tid + off];
    __syncthreads();
  }
  if (tid == 0) atomicAdd(&out[idx], sred[0] / num_valid[b]);
}

// ---------------------------------------------------------------------------
extern "C" void kernel_launch(void* const* d_in, const int* in_sizes, int n_in,
                              void* d_out, int out_size, void* d_ws,
                              size_t ws_size, hipStream_t stream) {
  const float* f_q = (const float*)d_in[0];
  const float* f_map = (const float*)d_in[1];
  const float* q_xy = (const float*)d_in[2];
  const float* temp = (const float*)d_in[3];
  const void* valid_q = d_in[4];    // numpy bool: width auto-detected
  const void* valid_map = d_in[5];  // numpy bool: width auto-detected
  const int* seedp = (const int*)d_in[6];
  float* out = (float*)d_out;

  char* ws = (char*)d_ws;
  float* num_valid = (float*)(ws + 0);
  int* n_idx = (int*)(ws + 256);
  int* bool_is32 = (int*)(ws + 4352);
  float4* poses = (float4*)(ws + 4608);
  float* row_m = (float*)(ws + 12800);
  float* row_s = (float*)(ws + 16896);
  float* row_th = (float*)(ws + 20992);
  u64* catbest = (u64*)(ws + 25088);
  float* pmax = (float*)(ws + 33280);           // 1024*128 f32 = 512 KB
  float* psum = (float*)(ws + 33280 + 524288);  // 512 KB

  setup_kernel<<<5, 256, 0, stream>>>(valid_q, seedp, num_valid, n_idx,
                                      bool_is32);
  cat1_kernel<<<dim3(NSEG, NGRP), 256, 0, stream>>>(f_q, f_map, temp, n_idx,
                                                    pmax, psum);
  catc_kernel<<<NB * 512, 128, 0, stream>>>(pmax, psum, row_m, row_s, row_th,
                                            catbest, out);
  cat2_kernel<<<dim3(NSEG, NGRP), 256, 0, stream>>>(
      f_q, f_map, temp, n_idx, row_m, row_s, row_th, num_valid, seedp, catbest);
  pose_kernel<<<2, 256, 0, stream>>>(q_xy, n_idx, catbest, poses);
  score_kernel<<<dim3(4, NB * KP), 256, 0, stream>>>(
      f_q, f_map, temp, q_xy, valid_q, valid_map, num_valid, poses, bool_is32,
      out);
}